// Round 4
// baseline (633.152 us; speedup 1.0000x reference)
//
#include <hip/hip_runtime.h>
#include <cstdint>
#include <cstddef>

#define BATCH 8
#define SEQ   2048
#define DM    1024
#define DE    2048   // D_MODEL*EXPAND
#define DSZ   256    // D_STATE
#define MROWS (BATCH*SEQ)  // 16384
#define MCHUNK 8192        // M rows per chunk (2 chunks)

typedef _Float16 f16;
typedef _Float16 f16x4 __attribute__((ext_vector_type(4)));
typedef _Float16 f16x8 __attribute__((ext_vector_type(8)));
typedef float  f32x4  __attribute__((ext_vector_type(4)));

// async global->LDS, 16B per lane (global_load_lds_dwordx4).
__device__ __forceinline__ void glds16(const void* gp, void* lp) {
  __builtin_amdgcn_global_load_lds(
      (const __attribute__((address_space(1))) void*)gp,
      (__attribute__((address_space(3))) void*)lp, 16, 0, 0);
}

__device__ __forceinline__ float silu_f(float x) {
  return x * __builtin_amdgcn_rcpf(1.0f + __expf(-x));
}

// ---------------- split fp32 -> hi/lo f16 (vectorized) ----------------
__global__ void split_x_k(const float* __restrict__ in, f16* __restrict__ oh,
                          f16* __restrict__ ol, int n) {
  int i = (blockIdx.x * blockDim.x + threadIdx.x) * 4;
  const int stride = gridDim.x * blockDim.x * 4;
  for (; i < n; i += stride) {
    float4 v = *(const float4*)(in + i);
    f16x4 h, l;
    h[0] = (f16)v.x; l[0] = (f16)(v.x - (float)h[0]);
    h[1] = (f16)v.y; l[1] = (f16)(v.y - (float)h[1]);
    h[2] = (f16)v.z; l[2] = (f16)(v.z - (float)h[2]);
    h[3] = (f16)v.w; l[3] = (f16)(v.w - (float)h[3]);
    *(f16x4*)(oh + i) = h;
    *(f16x4*)(ol + i) = l;
  }
}

// ---------------- transpose + split: in[R][C] fp32 -> hi/lo [C][R] f16 ----------------
__global__ void transpose_split_k(const float* __restrict__ in, f16* __restrict__ oh,
                                  f16* __restrict__ ol, int R, int C) {
  __shared__ float tile[32][33];
  const int c0 = blockIdx.x * 32, r0 = blockIdx.y * 32;
  const int tx = threadIdx.x, ty = threadIdx.y; // 32 x 8
  #pragma unroll
  for (int i = 0; i < 4; ++i)
    tile[ty + i*8][tx] = in[(size_t)(r0 + ty + i*8) * C + c0 + tx];
  __syncthreads();
  #pragma unroll
  for (int i = 0; i < 4; ++i) {
    float v = tile[tx][ty + i*8];
    f16 h = (f16)v;
    size_t idx = (size_t)(c0 + ty + i*8) * R + r0 + tx;
    oh[idx] = h;
    ol[idx] = (f16)(v - (float)h);
  }
}

// ---------------- transpose + cast to f16 ----------------
__global__ void transpose_cast_f16_k(const float* __restrict__ in, f16* __restrict__ out, int R, int C) {
  __shared__ float tile[32][33];
  const int c0 = blockIdx.x * 32, r0 = blockIdx.y * 32;
  const int tx = threadIdx.x, ty = threadIdx.y;
  #pragma unroll
  for (int i = 0; i < 4; ++i)
    tile[ty + i*8][tx] = in[(size_t)(r0 + ty + i*8) * C + c0 + tx];
  __syncthreads();
  #pragma unroll
  for (int i = 0; i < 4; ++i)
    out[(size_t)(c0 + ty + i*8) * R + r0 + tx] = (f16)tile[tx][ty + i*8];
}

// ---------------- GEMM1: xproj = silu(x @ W_in + b), pure-f16 hi/lo ----------------
// 512 threads, 8 waves, block tile 128x128, wave tile 64x32. K=1024, N=2048.
// A = xh/xl [Mchunk][1024], Bt = w_in hi/lo [2048][1024]. Out hi/lo f16.
__global__ __launch_bounds__(512) void gemm1_k(const f16* __restrict__ Ah, const f16* __restrict__ Al,
                                               const f16* __restrict__ Bh, const f16* __restrict__ Bl,
                                               const float* __restrict__ bias,
                                               f16* __restrict__ Ch, f16* __restrict__ Cl) {
  const int K = 1024, N = 2048;
  __shared__ f16 sAh[4096], sAl[4096], sBh[4096], sBl[4096];  // 8KB each = 32KB

  const int tid = threadIdx.x;
  const int w = tid >> 6, l = tid & 63;
  const int bm = blockIdx.y * 128, bn = blockIdx.x * 128;
  const int wm = (w >> 2) * 64, wn = (w & 3) * 32;
  const int lr = l & 15, lq = l >> 4;

  // staging: each tensor has 512 16B-chunks; thread stages chunk tid of each.
  const int r = tid >> 2, k8 = tid & 3;
  const f16* pAh = Ah + (size_t)(bm + r) * K + k8 * 8;
  const f16* pAl = Al + (size_t)(bm + r) * K + k8 * 8;
  const f16* pBh = Bh + (size_t)(bn + r) * K + k8 * 8;
  const f16* pBl = Bl + (size_t)(bn + r) * K + k8 * 8;
  f16* dAh = sAh + tid * 8; f16* dAl = sAl + tid * 8;
  f16* dBh = sBh + tid * 8; f16* dBl = sBl + tid * 8;

  int offA[4], offB[2];
  #pragma unroll
  for (int i = 0; i < 4; ++i) offA[i] = (wm + i*16 + lr) * 32 + lq * 8;
  #pragma unroll
  for (int j = 0; j < 2; ++j) offB[j] = (wn + j*16 + lr) * 32 + lq * 8;

  f32x4 acc[4][2] = {};

  for (int kk = 0; kk < K; kk += 32) {
    __syncthreads();
    glds16(pAh, dAh); glds16(pAl, dAl);
    glds16(pBh, dBh); glds16(pBl, dBl);
    pAh += 32; pAl += 32; pBh += 32; pBl += 32;
    asm volatile("s_waitcnt vmcnt(0)" ::: "memory");
    __syncthreads();

    f16x8 ah[4], al[4], bh[2], bl[2];
    #pragma unroll
    for (int i = 0; i < 4; ++i) {
      ah[i] = *(const f16x8*)(sAh + offA[i]);
      al[i] = *(const f16x8*)(sAl + offA[i]);
    }
    #pragma unroll
    for (int j = 0; j < 2; ++j) {
      bh[j] = *(const f16x8*)(sBh + offB[j]);
      bl[j] = *(const f16x8*)(sBl + offB[j]);
    }
    #pragma unroll
    for (int i = 0; i < 4; ++i)
      #pragma unroll
      for (int j = 0; j < 2; ++j) {
        acc[i][j] = __builtin_amdgcn_mfma_f32_16x16x32_f16(ah[i], bh[j], acc[i][j], 0, 0, 0);
        acc[i][j] = __builtin_amdgcn_mfma_f32_16x16x32_f16(ah[i], bl[j], acc[i][j], 0, 0, 0);
        acc[i][j] = __builtin_amdgcn_mfma_f32_16x16x32_f16(al[i], bh[j], acc[i][j], 0, 0, 0);
      }
  }

  // epilogue: C/D layout col = lane&15, row = (lane>>4)*4 + reg
  #pragma unroll
  for (int j = 0; j < 2; ++j) {
    const int col = bn + wn + j*16 + lr;
    const float bv = bias[col];
    #pragma unroll
    for (int i = 0; i < 4; ++i)
      #pragma unroll
      for (int r4 = 0; r4 < 4; ++r4) {
        const int row = bm + wm + i*16 + lq*4 + r4;
        const float s = silu_f(acc[i][j][r4] + bv);
        const f16 h = (f16)s;
        const size_t idx = (size_t)row * N + col;
        Ch[idx] = h;
        Cl[idx] = (f16)(s - (float)h);
      }
  }
}

// ---------------- GEMM2: upd = xproj @ W_state + b -> fp32 ----------------
// 256 threads, 4 waves, block tile 64x128, wave tile 32x64. K=2048, N=256.
__global__ __launch_bounds__(256) void gemm2s_k(const f16* __restrict__ Ah, const f16* __restrict__ Al,
                                                const f16* __restrict__ Bh, const f16* __restrict__ Bl,
                                                const float* __restrict__ bias,
                                                float* __restrict__ C) {
  const int K = 2048, N = 256;
  __shared__ f16 sAh[2048], sAl[2048], sBh[4096], sBl[4096];  // 4+4+8+8 KB

  const int tid = threadIdx.x;
  const int w = tid >> 6, l = tid & 63;
  const int bm = blockIdx.y * 64, bn = blockIdx.x * 128;
  const int wm = (w & 1) * 32, wn = (w >> 1) * 64;
  const int lr = l & 15, lq = l >> 4;

  // A: 256 chunks (one per thread); B: 512 chunks (two per thread)
  const int rA = tid >> 2, k8 = tid & 3;
  const f16* pAh = Ah + (size_t)(bm + rA) * K + k8 * 8;
  const f16* pAl = Al + (size_t)(bm + rA) * K + k8 * 8;
  f16* dAh = sAh + tid * 8; f16* dAl = sAl + tid * 8;
  const f16 *pBh[2], *pBl[2]; f16 *dBh[2], *dBl[2];
  #pragma unroll
  for (int p = 0; p < 2; ++p) {
    const int c = p * 256 + tid;
    const int rB = c >> 2;
    pBh[p] = Bh + (size_t)(bn + rB) * K + (c & 3) * 8;
    pBl[p] = Bl + (size_t)(bn + rB) * K + (c & 3) * 8;
    dBh[p] = sBh + (size_t)c * 8; dBl[p] = sBl + (size_t)c * 8;
  }

  int offA[2], offB[4];
  #pragma unroll
  for (int i = 0; i < 2; ++i) offA[i] = (wm + i*16 + lr) * 32 + lq * 8;
  #pragma unroll
  for (int j = 0; j < 4; ++j) offB[j] = (wn + j*16 + lr) * 32 + lq * 8;

  f32x4 acc[2][4] = {};

  for (int kk = 0; kk < K; kk += 32) {
    __syncthreads();
    glds16(pAh, dAh); glds16(pAl, dAl);
    pAh += 32; pAl += 32;
    #pragma unroll
    for (int p = 0; p < 2; ++p) {
      glds16(pBh[p], dBh[p]); pBh[p] += 32;
      glds16(pBl[p], dBl[p]); pBl[p] += 32;
    }
    asm volatile("s_waitcnt vmcnt(0)" ::: "memory");
    __syncthreads();

    f16x8 ah[2], al[2], bh[4], bl[4];
    #pragma unroll
    for (int i = 0; i < 2; ++i) {
      ah[i] = *(const f16x8*)(sAh + offA[i]);
      al[i] = *(const f16x8*)(sAl + offA[i]);
    }
    #pragma unroll
    for (int j = 0; j < 4; ++j) {
      bh[j] = *(const f16x8*)(sBh + offB[j]);
      bl[j] = *(const f16x8*)(sBl + offB[j]);
    }
    #pragma unroll
    for (int i = 0; i < 2; ++i)
      #pragma unroll
      for (int j = 0; j < 4; ++j) {
        acc[i][j] = __builtin_amdgcn_mfma_f32_16x16x32_f16(ah[i], bh[j], acc[i][j], 0, 0, 0);
        acc[i][j] = __builtin_amdgcn_mfma_f32_16x16x32_f16(ah[i], bl[j], acc[i][j], 0, 0, 0);
        acc[i][j] = __builtin_amdgcn_mfma_f32_16x16x32_f16(al[i], bh[j], acc[i][j], 0, 0, 0);
      }
  }

  #pragma unroll
  for (int j = 0; j < 4; ++j) {
    const int col = bn + wn + j*16 + lr;
    const float bv = bias[col];
    #pragma unroll
    for (int i = 0; i < 2; ++i)
      #pragma unroll
      for (int r4 = 0; r4 < 4; ++r4) {
        const int row = bm + wm + i*16 + lq*4 + r4;
        C[(size_t)row * N + col] = acc[i][j][r4] + bv;
      }
  }
}

// ---------------- GEMM3: out = states @ W_out + b -> fp32 (single f16) ----------------
// 256 threads, 128x128 tile, 4 waves 64x64. K=256, N=1024.
__global__ __launch_bounds__(256) void gemm3_k(const f16* __restrict__ A,
                                               const f16* __restrict__ Bt,
                                               const float* __restrict__ bias,
                                               float* __restrict__ C) {
  const int K = 256, N = 1024;
  __shared__ f16 sA[4096], sB[4096];

  const int tid = threadIdx.x;
  const int w = tid >> 6, l = tid & 63;
  const int bm = blockIdx.y * 128, bn = blockIdx.x * 128;
  const int wm = (w >> 1) * 64, wn = (w & 1) * 64;
  const int lr = l & 15, lq = l >> 4;

  const f16 *pA[2], *pB[2]; f16 *dA[2], *dB[2];
  #pragma unroll
  for (int p = 0; p < 2; ++p) {
    const int c = p * 256 + tid;
    const int r = c >> 2, k8 = c & 3;
    pA[p] = A  + (size_t)(bm + r) * K + k8 * 8;
    pB[p] = Bt + (size_t)(bn + r) * K + k8 * 8;
    dA[p] = sA + (size_t)c * 8;
    dB[p] = sB + (size_t)c * 8;
  }

  int offA[4], offB[4];
  #pragma unroll
  for (int i = 0; i < 4; ++i) {
    offA[i] = (wm + i*16 + lr) * 32 + lq * 8;
    offB[i] = (wn + i*16 + lr) * 32 + lq * 8;
  }

  f32x4 acc[4][4] = {};

  for (int kk = 0; kk < K; kk += 32) {
    __syncthreads();
    glds16(pA[0], dA[0]); glds16(pA[1], dA[1]);
    glds16(pB[0], dB[0]); glds16(pB[1], dB[1]);
    pA[0] += 32; pA[1] += 32; pB[0] += 32; pB[1] += 32;
    asm volatile("s_waitcnt vmcnt(0)" ::: "memory");
    __syncthreads();

    f16x8 af[4], bfr[4];
    #pragma unroll
    for (int i = 0; i < 4; ++i) af[i]  = *(const f16x8*)(sA + offA[i]);
    #pragma unroll
    for (int j = 0; j < 4; ++j) bfr[j] = *(const f16x8*)(sB + offB[j]);
    #pragma unroll
    for (int i = 0; i < 4; ++i)
      #pragma unroll
      for (int j = 0; j < 4; ++j)
        acc[i][j] = __builtin_amdgcn_mfma_f32_16x16x32_f16(af[i], bfr[j], acc[i][j], 0, 0, 0);
  }

  #pragma unroll
  for (int j = 0; j < 4; ++j) {
    const int col = bn + wn + j*16 + lr;
    const float bv = bias[col];
    #pragma unroll
    for (int i = 0; i < 4; ++i)
      #pragma unroll
      for (int r4 = 0; r4 < 4; ++r4) {
        const int row = bm + wm + i*16 + lq*4 + r4;
        C[(size_t)row * N + col] = acc[i][j][r4] + bv;
      }
  }
}

// ---------------- sequential scan: state = silu(state + u_t), fp32 -> f16 states ----------------
__global__ void scan_k(const float* __restrict__ upd, const float* __restrict__ init,
                       f16* __restrict__ states) {
  const int b = blockIdx.x, s = threadIdx.x;
  const float* u = upd + (size_t)b * SEQ * DSZ + s;
  f16* st = states + (size_t)b * SEQ * DSZ + s;
  float state = init[s];
  float ubuf[16];
  #pragma unroll
  for (int i = 0; i < 16; ++i) ubuf[i] = u[(size_t)i * DSZ];
  for (int t0 = 0; t0 < SEQ; t0 += 16) {
    #pragma unroll
    for (int i = 0; i < 16; ++i) {
      const int t = t0 + i;
      const float x = state + ubuf[i];
      state = silu_f(x);
      st[(size_t)t * DSZ] = (f16)state;
      const int tn = t + 16;
      ubuf[i] = (tn < SEQ) ? u[(size_t)tn * DSZ] : 0.0f;
    }
  }
}

extern "C" void kernel_launch(void* const* d_in, const int* in_sizes, int n_in,
                              void* d_out, int out_size, void* d_ws, size_t ws_size,
                              hipStream_t stream) {
  const float* x       = (const float*)d_in[0];
  const float* W_in    = (const float*)d_in[1];
  const float* b_in    = (const float*)d_in[2];
  const float* W_state = (const float*)d_in[3];
  const float* b_state = (const float*)d_in[4];
  const float* W_out   = (const float*)d_in[5];
  const float* b_out   = (const float*)d_in[6];
  const float* init_st = (const float*)d_in[7];
  float* out = (float*)d_out;

  char* ws = (char*)d_ws;
  f16*   xh        = (f16*)(ws + 0);             // 32MB [16384][1024]
  f16*   xl        = (f16*)(ws + 33554432);      // 32MB
  f16*   xproj_h   = (f16*)(ws + 67108864);      // 32MB [8192][2048] (per chunk)
  f16*   xproj_l   = (f16*)(ws + 100663296);     // 32MB
  float* upd       = (float*)(ws + 134217728);   // 16MB [16384][256] fp32
  f16*   states    = (f16*)(ws + 150994944);     // 8MB  [16384][256]
  f16*   w_in_h    = (f16*)(ws + 159383552);     // 4MB  [2048][1024]
  f16*   w_in_l    = (f16*)(ws + 163577856);     // 4MB
  f16*   w_state_h = (f16*)(ws + 167772160);     // 1MB  [256][2048]
  f16*   w_state_l = (f16*)(ws + 168820736);     // 1MB
  f16*   w_out_t   = (f16*)(ws + 169869312);     // 0.5MB [1024][256]  (end = 170,393,600 B)

  // 1) pre-split x, transpose+split weights
  split_x_k<<<4096, 256, 0, stream>>>(x, xh, xl, MROWS * DM);
  dim3 tb(32, 8);
  transpose_split_k<<<dim3(DE/32,  DM/32), tb, 0, stream>>>(W_in,    w_in_h,    w_in_l,    DM,  DE);
  transpose_split_k<<<dim3(DSZ/32, DE/32), tb, 0, stream>>>(W_state, w_state_h, w_state_l, DE,  DSZ);
  transpose_cast_f16_k<<<dim3(DM/32, DSZ/32), tb, 0, stream>>>(W_out, w_out_t, DSZ, DM);

  // 2/3) chunked: xproj = silu(x@W_in+b) -> hi/lo f16; upd = xproj@W_state+b -> fp32
  for (int c = 0; c < 2; ++c) {
    const size_t ro = (size_t)c * MCHUNK;
    gemm1_k<<<dim3(DE/128, MCHUNK/128), 512, 0, stream>>>(
        xh + ro * DM, xl + ro * DM, w_in_h, w_in_l, b_in, xproj_h, xproj_l);
    gemm2s_k<<<dim3(DSZ/128, MCHUNK/64), 256, 0, stream>>>(
        xproj_h, xproj_l, w_state_h, w_state_l, b_state, upd + ro * DSZ);
  }

  // 4) sequential scan (fp32), states as f16
  scan_k<<<BATCH, DSZ, 0, stream>>>(upd, init_st, states);

  // 5) out = states @ W_out + b_out -> fp32
  gemm3_k<<<dim3(DM/128, MROWS/128), 256, 0, stream>>>(states, w_out_t, b_out, out);
}

// Round 5
// 625.372 us; speedup vs baseline: 1.0124x; 1.0124x over previous
//
#include <hip/hip_runtime.h>
#include <cstdint>
#include <cstddef>

#define BATCH 8
#define SEQ   2048
#define DM    1024
#define DE    2048   // D_MODEL*EXPAND
#define DSZ   256    // D_STATE
#define MROWS (BATCH*SEQ)  // 16384
#define MCHUNK 8192        // M rows per chunk (2 chunks)

typedef _Float16 f16;
typedef _Float16 f16x4 __attribute__((ext_vector_type(4)));
typedef _Float16 f16x8 __attribute__((ext_vector_type(8)));
typedef float  f32x4  __attribute__((ext_vector_type(4)));

// async global->LDS, 16B per lane (global_load_lds_dwordx4).
__device__ __forceinline__ void glds16(const void* gp, void* lp) {
  __builtin_amdgcn_global_load_lds(
      (const __attribute__((address_space(1))) void*)gp,
      (__attribute__((address_space(3))) void*)lp, 16, 0, 0);
}

__device__ __forceinline__ float silu_f(float x) {
  return x * __builtin_amdgcn_rcpf(1.0f + __expf(-x));
}

// ---------------- split fp32 -> hi/lo f16 (vectorized) ----------------
__global__ void split_x_k(const float* __restrict__ in, f16* __restrict__ oh,
                          f16* __restrict__ ol, int n) {
  int i = (blockIdx.x * blockDim.x + threadIdx.x) * 4;
  const int stride = gridDim.x * blockDim.x * 4;
  for (; i < n; i += stride) {
    float4 v = *(const float4*)(in + i);
    f16x4 h, l;
    h[0] = (f16)v.x; l[0] = (f16)(v.x - (float)h[0]);
    h[1] = (f16)v.y; l[1] = (f16)(v.y - (float)h[1]);
    h[2] = (f16)v.z; l[2] = (f16)(v.z - (float)h[2]);
    h[3] = (f16)v.w; l[3] = (f16)(v.w - (float)h[3]);
    *(f16x4*)(oh + i) = h;
    *(f16x4*)(ol + i) = l;
  }
}

// ---------------- transpose + split: in[R][C] fp32 -> hi/lo [C][R] f16 ----------------
__global__ void transpose_split_k(const float* __restrict__ in, f16* __restrict__ oh,
                                  f16* __restrict__ ol, int R, int C) {
  __shared__ float tile[32][33];
  const int c0 = blockIdx.x * 32, r0 = blockIdx.y * 32;
  const int tx = threadIdx.x, ty = threadIdx.y; // 32 x 8
  #pragma unroll
  for (int i = 0; i < 4; ++i)
    tile[ty + i*8][tx] = in[(size_t)(r0 + ty + i*8) * C + c0 + tx];
  __syncthreads();
  #pragma unroll
  for (int i = 0; i < 4; ++i) {
    float v = tile[tx][ty + i*8];
    f16 h = (f16)v;
    size_t idx = (size_t)(c0 + ty + i*8) * R + r0 + tx;
    oh[idx] = h;
    ol[idx] = (f16)(v - (float)h);
  }
}

// ---------------- transpose + cast to f16 ----------------
__global__ void transpose_cast_f16_k(const float* __restrict__ in, f16* __restrict__ out, int R, int C) {
  __shared__ float tile[32][33];
  const int c0 = blockIdx.x * 32, r0 = blockIdx.y * 32;
  const int tx = threadIdx.x, ty = threadIdx.y;
  #pragma unroll
  for (int i = 0; i < 4; ++i)
    tile[ty + i*8][tx] = in[(size_t)(r0 + ty + i*8) * C + c0 + tx];
  __syncthreads();
  #pragma unroll
  for (int i = 0; i < 4; ++i)
    out[(size_t)(c0 + ty + i*8) * R + r0 + tx] = (f16)tile[tx][ty + i*8];
}

// ---------------- GEMM1: xproj = silu(x @ W_in + b), pure-f16 hi/lo ----------------
// 512 threads, 8 waves, block tile 128x128, wave tile 64x32. K=1024, N=2048.
// 1D grid (1024 blocks), XCD-aware supertile swizzle: each XCD owns an
// 8-M-tile stripe across all 16 N-tiles (A stripe = 4MB fits per-XCD L2;
// B-tile reused by 8 consecutive same-XCD blocks).
__global__ __launch_bounds__(512) void gemm1_k(const f16* __restrict__ Ah, const f16* __restrict__ Al,
                                               const f16* __restrict__ Bh, const f16* __restrict__ Bl,
                                               const float* __restrict__ bias,
                                               f16* __restrict__ Ch, f16* __restrict__ Cl) {
  const int K = 1024, N = 2048;
  __shared__ f16 sAh[4096], sAl[4096], sBh[4096], sBl[4096];  // 8KB each = 32KB

  const int tid = threadIdx.x;
  const int w = tid >> 6, l = tid & 63;
  const int bid = blockIdx.x;              // 0..1023
  const int xcd = bid & 7, loc = bid >> 3; // loc 0..127
  const int mt = xcd * 8 + (loc & 7);      // 0..63
  const int nt = loc >> 3;                 // 0..15
  const int bm = mt * 128, bn = nt * 128;
  const int wm = (w >> 2) * 64, wn = (w & 3) * 32;
  const int lr = l & 15, lq = l >> 4;

  // staging: each tensor has 512 16B-chunks; thread stages chunk tid of each.
  const int r = tid >> 2, k8 = tid & 3;
  const f16* pAh = Ah + (size_t)(bm + r) * K + k8 * 8;
  const f16* pAl = Al + (size_t)(bm + r) * K + k8 * 8;
  const f16* pBh = Bh + (size_t)(bn + r) * K + k8 * 8;
  const f16* pBl = Bl + (size_t)(bn + r) * K + k8 * 8;
  f16* dAh = sAh + tid * 8; f16* dAl = sAl + tid * 8;
  f16* dBh = sBh + tid * 8; f16* dBl = sBl + tid * 8;

  int offA[4], offB[2];
  #pragma unroll
  for (int i = 0; i < 4; ++i) offA[i] = (wm + i*16 + lr) * 32 + lq * 8;
  #pragma unroll
  for (int j = 0; j < 2; ++j) offB[j] = (wn + j*16 + lr) * 32 + lq * 8;

  f32x4 acc[4][2] = {};

  for (int kk = 0; kk < K; kk += 32) {
    __syncthreads();
    glds16(pAh, dAh); glds16(pAl, dAl);
    glds16(pBh, dBh); glds16(pBl, dBl);
    pAh += 32; pAl += 32; pBh += 32; pBl += 32;
    asm volatile("s_waitcnt vmcnt(0)" ::: "memory");
    __syncthreads();

    f16x8 ah[4], al[4], bh[2], bl[2];
    #pragma unroll
    for (int i = 0; i < 4; ++i) {
      ah[i] = *(const f16x8*)(sAh + offA[i]);
      al[i] = *(const f16x8*)(sAl + offA[i]);
    }
    #pragma unroll
    for (int j = 0; j < 2; ++j) {
      bh[j] = *(const f16x8*)(sBh + offB[j]);
      bl[j] = *(const f16x8*)(sBl + offB[j]);
    }
    #pragma unroll
    for (int i = 0; i < 4; ++i)
      #pragma unroll
      for (int j = 0; j < 2; ++j) {
        acc[i][j] = __builtin_amdgcn_mfma_f32_16x16x32_f16(ah[i], bh[j], acc[i][j], 0, 0, 0);
        acc[i][j] = __builtin_amdgcn_mfma_f32_16x16x32_f16(ah[i], bl[j], acc[i][j], 0, 0, 0);
        acc[i][j] = __builtin_amdgcn_mfma_f32_16x16x32_f16(al[i], bh[j], acc[i][j], 0, 0, 0);
      }
  }

  // epilogue: C/D layout col = lane&15, row = (lane>>4)*4 + reg
  #pragma unroll
  for (int j = 0; j < 2; ++j) {
    const int col = bn + wn + j*16 + lr;
    const float bv = bias[col];
    #pragma unroll
    for (int i = 0; i < 4; ++i)
      #pragma unroll
      for (int r4 = 0; r4 < 4; ++r4) {
        const int row = bm + wm + i*16 + lq*4 + r4;
        const float s = silu_f(acc[i][j][r4] + bv);
        const f16 h = (f16)s;
        const size_t idx = (size_t)row * N + col;
        Ch[idx] = h;
        Cl[idx] = (f16)(s - (float)h);
      }
  }
}

// ---------------- GEMM2: upd = xproj @ W_state + b -> fp32 ----------------
// 256 threads, 4 waves, block tile 64x128, wave tile 32x64. K=2048, N=256.
__global__ __launch_bounds__(256) void gemm2s_k(const f16* __restrict__ Ah, const f16* __restrict__ Al,
                                                const f16* __restrict__ Bh, const f16* __restrict__ Bl,
                                                const float* __restrict__ bias,
                                                float* __restrict__ C) {
  const int K = 2048, N = 256;
  __shared__ f16 sAh[2048], sAl[2048], sBh[4096], sBl[4096];  // 4+4+8+8 KB

  const int tid = threadIdx.x;
  const int w = tid >> 6, l = tid & 63;
  const int bm = blockIdx.y * 64, bn = blockIdx.x * 128;
  const int wm = (w & 1) * 32, wn = (w >> 1) * 64;
  const int lr = l & 15, lq = l >> 4;

  // A: 256 chunks (one per thread); B: 512 chunks (two per thread)
  const int rA = tid >> 2, k8 = tid & 3;
  const f16* pAh = Ah + (size_t)(bm + rA) * K + k8 * 8;
  const f16* pAl = Al + (size_t)(bm + rA) * K + k8 * 8;
  f16* dAh = sAh + tid * 8; f16* dAl = sAl + tid * 8;
  const f16 *pBh[2], *pBl[2]; f16 *dBh[2], *dBl[2];
  #pragma unroll
  for (int p = 0; p < 2; ++p) {
    const int c = p * 256 + tid;
    const int rB = c >> 2;
    pBh[p] = Bh + (size_t)(bn + rB) * K + (c & 3) * 8;
    pBl[p] = Bl + (size_t)(bn + rB) * K + (c & 3) * 8;
    dBh[p] = sBh + (size_t)c * 8; dBl[p] = sBl + (size_t)c * 8;
  }

  int offA[2], offB[4];
  #pragma unroll
  for (int i = 0; i < 2; ++i) offA[i] = (wm + i*16 + lr) * 32 + lq * 8;
  #pragma unroll
  for (int j = 0; j < 4; ++j) offB[j] = (wn + j*16 + lr) * 32 + lq * 8;

  f32x4 acc[2][4] = {};

  for (int kk = 0; kk < K; kk += 32) {
    __syncthreads();
    glds16(pAh, dAh); glds16(pAl, dAl);
    pAh += 32; pAl += 32;
    #pragma unroll
    for (int p = 0; p < 2; ++p) {
      glds16(pBh[p], dBh[p]); pBh[p] += 32;
      glds16(pBl[p], dBl[p]); pBl[p] += 32;
    }
    asm volatile("s_waitcnt vmcnt(0)" ::: "memory");
    __syncthreads();

    f16x8 ah[2], al[2], bh[4], bl[4];
    #pragma unroll
    for (int i = 0; i < 2; ++i) {
      ah[i] = *(const f16x8*)(sAh + offA[i]);
      al[i] = *(const f16x8*)(sAl + offA[i]);
    }
    #pragma unroll
    for (int j = 0; j < 4; ++j) {
      bh[j] = *(const f16x8*)(sBh + offB[j]);
      bl[j] = *(const f16x8*)(sBl + offB[j]);
    }
    #pragma unroll
    for (int i = 0; i < 2; ++i)
      #pragma unroll
      for (int j = 0; j < 4; ++j) {
        acc[i][j] = __builtin_amdgcn_mfma_f32_16x16x32_f16(ah[i], bh[j], acc[i][j], 0, 0, 0);
        acc[i][j] = __builtin_amdgcn_mfma_f32_16x16x32_f16(ah[i], bl[j], acc[i][j], 0, 0, 0);
        acc[i][j] = __builtin_amdgcn_mfma_f32_16x16x32_f16(al[i], bh[j], acc[i][j], 0, 0, 0);
      }
  }

  #pragma unroll
  for (int j = 0; j < 4; ++j) {
    const int col = bn + wn + j*16 + lr;
    const float bv = bias[col];
    #pragma unroll
    for (int i = 0; i < 2; ++i)
      #pragma unroll
      for (int r4 = 0; r4 < 4; ++r4) {
        const int row = bm + wm + i*16 + lq*4 + r4;
        C[(size_t)row * N + col] = acc[i][j][r4] + bv;
      }
  }
}

// ---------------- GEMM3: out = states @ W_out + b -> fp32 (single f16) ----------------
__global__ __launch_bounds__(256) void gemm3_k(const f16* __restrict__ A,
                                               const f16* __restrict__ Bt,
                                               const float* __restrict__ bias,
                                               float* __restrict__ C) {
  const int K = 256, N = 1024;
  __shared__ f16 sA[4096], sB[4096];

  const int tid = threadIdx.x;
  const int w = tid >> 6, l = tid & 63;
  const int bm = blockIdx.y * 128, bn = blockIdx.x * 128;
  const int wm = (w >> 1) * 64, wn = (w & 1) * 64;
  const int lr = l & 15, lq = l >> 4;

  const f16 *pA[2], *pB[2]; f16 *dA[2], *dB[2];
  #pragma unroll
  for (int p = 0; p < 2; ++p) {
    const int c = p * 256 + tid;
    const int r = c >> 2, k8 = c & 3;
    pA[p] = A  + (size_t)(bm + r) * K + k8 * 8;
    pB[p] = Bt + (size_t)(bn + r) * K + k8 * 8;
    dA[p] = sA + (size_t)c * 8;
    dB[p] = sB + (size_t)c * 8;
  }

  int offA[4], offB[4];
  #pragma unroll
  for (int i = 0; i < 4; ++i) {
    offA[i] = (wm + i*16 + lr) * 32 + lq * 8;
    offB[i] = (wn + i*16 + lr) * 32 + lq * 8;
  }

  f32x4 acc[4][4] = {};

  for (int kk = 0; kk < K; kk += 32) {
    __syncthreads();
    glds16(pA[0], dA[0]); glds16(pA[1], dA[1]);
    glds16(pB[0], dB[0]); glds16(pB[1], dB[1]);
    pA[0] += 32; pA[1] += 32; pB[0] += 32; pB[1] += 32;
    asm volatile("s_waitcnt vmcnt(0)" ::: "memory");
    __syncthreads();

    f16x8 af[4], bfr[4];
    #pragma unroll
    for (int i = 0; i < 4; ++i) af[i]  = *(const f16x8*)(sA + offA[i]);
    #pragma unroll
    for (int j = 0; j < 4; ++j) bfr[j] = *(const f16x8*)(sB + offB[j]);
    #pragma unroll
    for (int i = 0; i < 4; ++i)
      #pragma unroll
      for (int j = 0; j < 4; ++j)
        acc[i][j] = __builtin_amdgcn_mfma_f32_16x16x32_f16(af[i], bfr[j], acc[i][j], 0, 0, 0);
  }

  #pragma unroll
  for (int j = 0; j < 4; ++j) {
    const int col = bn + wn + j*16 + lr;
    const float bv = bias[col];
    #pragma unroll
    for (int i = 0; i < 4; ++i)
      #pragma unroll
      for (int r4 = 0; r4 < 4; ++r4) {
        const int row = bm + wm + i*16 + lq*4 + r4;
        C[(size_t)row * N + col] = acc[i][j][r4] + bv;
      }
  }
}

// ---------------- sequential scan: state = silu(state + u_t), fp32 -> f16 states ----------------
// Blocked: 16 loads -> 16 pure-register silu steps -> 16 stores. Chain per step:
// fma(state,-log2e,ulog) -> exp2 -> add1 -> rcp -> mul  (x=state+u runs in parallel).
#define L2E 1.4426950408889634f
__global__ void scan_k(const float* __restrict__ upd, const float* __restrict__ init,
                       f16* __restrict__ states) {
  const int b = blockIdx.x, s = threadIdx.x;
  const float* u = upd + (size_t)b * SEQ * DSZ + s;
  f16* st = states + (size_t)b * SEQ * DSZ + s;
  float state = init[s];

  float ucur[16], unext[16], ulog[16];
  #pragma unroll
  for (int i = 0; i < 16; ++i) ucur[i] = u[(size_t)i * DSZ];
  #pragma unroll
  for (int i = 0; i < 16; ++i) ulog[i] = ucur[i] * (-L2E);

  for (int t0 = 0; t0 < SEQ; t0 += 16) {
    // issue next block's loads (off the dependency chain)
    if (t0 + 16 < SEQ) {
      #pragma unroll
      for (int i = 0; i < 16; ++i) unext[i] = u[(size_t)(t0 + 16 + i) * DSZ];
    }
    // pure-register dependent chain
    f16 res[16];
    #pragma unroll
    for (int i = 0; i < 16; ++i) {
      const float e = __builtin_amdgcn_exp2f(__builtin_fmaf(state, -L2E, ulog[i]));
      const float x = state + ucur[i];
      state = x * __builtin_amdgcn_rcpf(1.0f + e);
      res[i] = (f16)state;
    }
    // stores (off-chain)
    #pragma unroll
    for (int i = 0; i < 16; ++i) st[(size_t)(t0 + i) * DSZ] = res[i];
    // rotate
    #pragma unroll
    for (int i = 0; i < 16; ++i) { ucur[i] = unext[i]; ulog[i] = unext[i] * (-L2E); }
  }
}

extern "C" void kernel_launch(void* const* d_in, const int* in_sizes, int n_in,
                              void* d_out, int out_size, void* d_ws, size_t ws_size,
                              hipStream_t stream) {
  const float* x       = (const float*)d_in[0];
  const float* W_in    = (const float*)d_in[1];
  const float* b_in    = (const float*)d_in[2];
  const float* W_state = (const float*)d_in[3];
  const float* b_state = (const float*)d_in[4];
  const float* W_out   = (const float*)d_in[5];
  const float* b_out   = (const float*)d_in[6];
  const float* init_st = (const float*)d_in[7];
  float* out = (float*)d_out;

  char* ws = (char*)d_ws;
  f16*   xh        = (f16*)(ws + 0);             // 32MB [16384][1024]
  f16*   xl        = (f16*)(ws + 33554432);      // 32MB
  f16*   xproj_h   = (f16*)(ws + 67108864);      // 32MB [8192][2048] (per chunk)
  f16*   xproj_l   = (f16*)(ws + 100663296);     // 32MB
  float* upd       = (float*)(ws + 134217728);   // 16MB [16384][256] fp32
  f16*   states    = (f16*)(ws + 150994944);     // 8MB  [16384][256]
  f16*   w_in_h    = (f16*)(ws + 159383552);     // 4MB  [2048][1024]
  f16*   w_in_l    = (f16*)(ws + 163577856);     // 4MB
  f16*   w_state_h = (f16*)(ws + 167772160);     // 1MB  [256][2048]
  f16*   w_state_l = (f16*)(ws + 168820736);     // 1MB
  f16*   w_out_t   = (f16*)(ws + 169869312);     // 0.5MB [1024][256]  (end = 170,393,600 B)

  // 1) pre-split x, transpose+split weights
  split_x_k<<<4096, 256, 0, stream>>>(x, xh, xl, MROWS * DM);
  dim3 tb(32, 8);
  transpose_split_k<<<dim3(DE/32,  DM/32), tb, 0, stream>>>(W_in,    w_in_h,    w_in_l,    DM,  DE);
  transpose_split_k<<<dim3(DSZ/32, DE/32), tb, 0, stream>>>(W_state, w_state_h, w_state_l, DE,  DSZ);
  transpose_cast_f16_k<<<dim3(DM/32, DSZ/32), tb, 0, stream>>>(W_out, w_out_t, DSZ, DM);

  // 2/3) chunked: xproj = silu(x@W_in+b) -> hi/lo f16; upd = xproj@W_state+b -> fp32
  for (int c = 0; c < 2; ++c) {
    const size_t ro = (size_t)c * MCHUNK;
    gemm1_k<<<1024, 512, 0, stream>>>(
        xh + ro * DM, xl + ro * DM, w_in_h, w_in_l, b_in, xproj_h, xproj_l);
    gemm2s_k<<<dim3(DSZ/128, MCHUNK/64), 256, 0, stream>>>(
        xproj_h, xproj_l, w_state_h, w_state_l, b_state, upd + ro * DSZ);
  }

  // 4) sequential scan (fp32), states as f16
  scan_k<<<BATCH, DSZ, 0, stream>>>(upd, init_st, states);

  // 5) out = states @ W_out + b_out -> fp32
  gemm3_k<<<dim3(DM/128, MROWS/128), 256, 0, stream>>>(states, w_out_t, b_out, out);
}

// Round 6
// 592.624 us; speedup vs baseline: 1.0684x; 1.0553x over previous
//
#include <hip/hip_runtime.h>
#include <cstdint>
#include <cstddef>

#define BATCH 8
#define SEQ   2048
#define DM    1024
#define DE    2048   // D_MODEL*EXPAND
#define DSZ   256    // D_STATE
#define MROWS (BATCH*SEQ)  // 16384
#define MCHUNK 8192        // M rows per chunk (2 chunks)

typedef _Float16 f16;
typedef _Float16 f16x4 __attribute__((ext_vector_type(4)));
typedef _Float16 f16x8 __attribute__((ext_vector_type(8)));
typedef float  f32x4  __attribute__((ext_vector_type(4)));

// async global->LDS, 16B per lane (global_load_lds_dwordx4).
__device__ __forceinline__ void glds16(const void* gp, void* lp) {
  __builtin_amdgcn_global_load_lds(
      (const __attribute__((address_space(1))) void*)gp,
      (__attribute__((address_space(3))) void*)lp, 16, 0, 0);
}

__device__ __forceinline__ float silu_f(float x) {
  return x * __builtin_amdgcn_rcpf(1.0f + __expf(-x));
}

// LDS XOR-swizzle: 16B-chunk k8 within a 64B row is permuted by ((row>>1)&3)
// so fragment reads are 2-way-per-bank-group (free) instead of 8-way.
__device__ __forceinline__ int swz(int k8, int r) { return k8 ^ ((r >> 1) & 3); }

// ---------------- split fp32 -> hi/lo f16 (vectorized) ----------------
__global__ void split_x_k(const float* __restrict__ in, f16* __restrict__ oh,
                          f16* __restrict__ ol, int n) {
  int i = (blockIdx.x * blockDim.x + threadIdx.x) * 4;
  const int stride = gridDim.x * blockDim.x * 4;
  for (; i < n; i += stride) {
    float4 v = *(const float4*)(in + i);
    f16x4 h, l;
    h[0] = (f16)v.x; l[0] = (f16)(v.x - (float)h[0]);
    h[1] = (f16)v.y; l[1] = (f16)(v.y - (float)h[1]);
    h[2] = (f16)v.z; l[2] = (f16)(v.z - (float)h[2]);
    h[3] = (f16)v.w; l[3] = (f16)(v.w - (float)h[3]);
    *(f16x4*)(oh + i) = h;
    *(f16x4*)(ol + i) = l;
  }
}

// ---------------- transpose + split: in[R][C] fp32 -> hi/lo [C][R] f16 ----------------
__global__ void transpose_split_k(const float* __restrict__ in, f16* __restrict__ oh,
                                  f16* __restrict__ ol, int R, int C) {
  __shared__ float tile[32][33];
  const int c0 = blockIdx.x * 32, r0 = blockIdx.y * 32;
  const int tx = threadIdx.x, ty = threadIdx.y; // 32 x 8
  #pragma unroll
  for (int i = 0; i < 4; ++i)
    tile[ty + i*8][tx] = in[(size_t)(r0 + ty + i*8) * C + c0 + tx];
  __syncthreads();
  #pragma unroll
  for (int i = 0; i < 4; ++i) {
    float v = tile[tx][ty + i*8];
    f16 h = (f16)v;
    size_t idx = (size_t)(c0 + ty + i*8) * R + r0 + tx;
    oh[idx] = h;
    ol[idx] = (f16)(v - (float)h);
  }
}

// ---------------- transpose + cast to f16 ----------------
__global__ void transpose_cast_f16_k(const float* __restrict__ in, f16* __restrict__ out, int R, int C) {
  __shared__ float tile[32][33];
  const int c0 = blockIdx.x * 32, r0 = blockIdx.y * 32;
  const int tx = threadIdx.x, ty = threadIdx.y;
  #pragma unroll
  for (int i = 0; i < 4; ++i)
    tile[ty + i*8][tx] = in[(size_t)(r0 + ty + i*8) * C + c0 + tx];
  __syncthreads();
  #pragma unroll
  for (int i = 0; i < 4; ++i)
    out[(size_t)(c0 + ty + i*8) * R + r0 + tx] = (f16)tile[tx][ty + i*8];
}

// ---------------- GEMM1: xproj = silu(x @ W_in + b), pure-f16 hi/lo ----------------
// 512 threads, 8 waves, block tile 128x128, wave tile 64x32. K=1024, N=2048.
// XCD-aware supertile swizzle + LDS XOR-swizzle (conflict-free frag reads).
__global__ __launch_bounds__(512) void gemm1_k(const f16* __restrict__ Ah, const f16* __restrict__ Al,
                                               const f16* __restrict__ Bh, const f16* __restrict__ Bl,
                                               const float* __restrict__ bias,
                                               f16* __restrict__ Ch, f16* __restrict__ Cl) {
  const int K = 1024, N = 2048;
  __shared__ f16 sAh[4096], sAl[4096], sBh[4096], sBl[4096];  // 8KB each = 32KB

  const int tid = threadIdx.x;
  const int w = tid >> 6, l = tid & 63;
  const int bid = blockIdx.x;              // 0..1023
  const int xcd = bid & 7, loc = bid >> 3; // loc 0..127
  const int mt = xcd * 8 + (loc & 7);      // 0..63
  const int nt = loc >> 3;                 // 0..15
  const int bm = mt * 128, bn = nt * 128;
  const int wm = (w >> 2) * 64, wn = (w & 3) * 32;
  const int lr = l & 15, lq = l >> 4;

  // staging: chunk tid of each tensor; LDS chunk tid holds global chunk (r, swz(k8,r))
  const int r = tid >> 2, k8 = swz(tid & 3, r);
  const f16* pAh = Ah + (size_t)(bm + r) * K + k8 * 8;
  const f16* pAl = Al + (size_t)(bm + r) * K + k8 * 8;
  const f16* pBh = Bh + (size_t)(bn + r) * K + k8 * 8;
  const f16* pBl = Bl + (size_t)(bn + r) * K + k8 * 8;
  f16* dAh = sAh + tid * 8; f16* dAl = sAl + tid * 8;
  f16* dBh = sBh + tid * 8; f16* dBl = sBl + tid * 8;

  int offA[4], offB[2];
  #pragma unroll
  for (int i = 0; i < 4; ++i) {
    const int row = wm + i*16 + lr;
    offA[i] = row * 32 + swz(lq, row) * 8;
  }
  #pragma unroll
  for (int j = 0; j < 2; ++j) {
    const int row = wn + j*16 + lr;
    offB[j] = row * 32 + swz(lq, row) * 8;
  }

  f32x4 acc[4][2] = {};

  for (int kk = 0; kk < K; kk += 32) {
    __syncthreads();
    glds16(pAh, dAh); glds16(pAl, dAl);
    glds16(pBh, dBh); glds16(pBl, dBl);
    pAh += 32; pAl += 32; pBh += 32; pBl += 32;
    asm volatile("s_waitcnt vmcnt(0)" ::: "memory");
    __syncthreads();

    f16x8 ah[4], al[4], bh[2], bl[2];
    #pragma unroll
    for (int i = 0; i < 4; ++i) {
      ah[i] = *(const f16x8*)(sAh + offA[i]);
      al[i] = *(const f16x8*)(sAl + offA[i]);
    }
    #pragma unroll
    for (int j = 0; j < 2; ++j) {
      bh[j] = *(const f16x8*)(sBh + offB[j]);
      bl[j] = *(const f16x8*)(sBl + offB[j]);
    }
    #pragma unroll
    for (int i = 0; i < 4; ++i)
      #pragma unroll
      for (int j = 0; j < 2; ++j) {
        acc[i][j] = __builtin_amdgcn_mfma_f32_16x16x32_f16(ah[i], bh[j], acc[i][j], 0, 0, 0);
        acc[i][j] = __builtin_amdgcn_mfma_f32_16x16x32_f16(ah[i], bl[j], acc[i][j], 0, 0, 0);
        acc[i][j] = __builtin_amdgcn_mfma_f32_16x16x32_f16(al[i], bh[j], acc[i][j], 0, 0, 0);
      }
  }

  // epilogue: C/D layout col = lane&15, row = (lane>>4)*4 + reg
  #pragma unroll
  for (int j = 0; j < 2; ++j) {
    const int col = bn + wn + j*16 + lr;
    const float bv = bias[col];
    #pragma unroll
    for (int i = 0; i < 4; ++i)
      #pragma unroll
      for (int r4 = 0; r4 < 4; ++r4) {
        const int row = bm + wm + i*16 + lq*4 + r4;
        const float s = silu_f(acc[i][j][r4] + bv);
        const f16 h = (f16)s;
        const size_t idx = (size_t)row * N + col;
        Ch[idx] = h;
        Cl[idx] = (f16)(s - (float)h);
      }
  }
}

// ---------------- GEMM2: upd = xproj @ W_state + b -> fp32 ----------------
// 256 threads, 4 waves, block tile 64x64, wave tile 32x32. K=2048, N=256.
// Grid 512 blocks = 2/CU so co-resident blocks overlap staging drains.
__global__ __launch_bounds__(256) void gemm2s_k(const f16* __restrict__ Ah, const f16* __restrict__ Al,
                                                const f16* __restrict__ Bh, const f16* __restrict__ Bl,
                                                const float* __restrict__ bias,
                                                float* __restrict__ C) {
  const int K = 2048, N = 256;
  __shared__ f16 sAh[2048], sAl[2048], sBh[2048], sBl[2048];  // 4KB each = 16KB

  const int tid = threadIdx.x;
  const int w = tid >> 6, l = tid & 63;
  const int bm = blockIdx.y * 64, bn = blockIdx.x * 64;
  const int wm = (w & 1) * 32, wn = (w >> 1) * 32;
  const int lr = l & 15, lq = l >> 4;

  // each tensor: 64 rows x 32 k = 256 chunks; thread stages chunk tid of each
  const int r = tid >> 2, k8 = swz(tid & 3, r);
  const f16* pAh = Ah + (size_t)(bm + r) * K + k8 * 8;
  const f16* pAl = Al + (size_t)(bm + r) * K + k8 * 8;
  const f16* pBh = Bh + (size_t)(bn + r) * K + k8 * 8;
  const f16* pBl = Bl + (size_t)(bn + r) * K + k8 * 8;
  f16* dAh = sAh + tid * 8; f16* dAl = sAl + tid * 8;
  f16* dBh = sBh + tid * 8; f16* dBl = sBl + tid * 8;

  int offA[2], offB[2];
  #pragma unroll
  for (int i = 0; i < 2; ++i) {
    const int row = wm + i*16 + lr;
    offA[i] = row * 32 + swz(lq, row) * 8;
  }
  #pragma unroll
  for (int j = 0; j < 2; ++j) {
    const int row = wn + j*16 + lr;
    offB[j] = row * 32 + swz(lq, row) * 8;
  }

  f32x4 acc[2][2] = {};

  for (int kk = 0; kk < K; kk += 32) {
    __syncthreads();
    glds16(pAh, dAh); glds16(pAl, dAl);
    glds16(pBh, dBh); glds16(pBl, dBl);
    pAh += 32; pAl += 32; pBh += 32; pBl += 32;
    asm volatile("s_waitcnt vmcnt(0)" ::: "memory");
    __syncthreads();

    f16x8 ah[2], al[2], bh[2], bl[2];
    #pragma unroll
    for (int i = 0; i < 2; ++i) {
      ah[i] = *(const f16x8*)(sAh + offA[i]);
      al[i] = *(const f16x8*)(sAl + offA[i]);
    }
    #pragma unroll
    for (int j = 0; j < 2; ++j) {
      bh[j] = *(const f16x8*)(sBh + offB[j]);
      bl[j] = *(const f16x8*)(sBl + offB[j]);
    }
    #pragma unroll
    for (int i = 0; i < 2; ++i)
      #pragma unroll
      for (int j = 0; j < 2; ++j) {
        acc[i][j] = __builtin_amdgcn_mfma_f32_16x16x32_f16(ah[i], bh[j], acc[i][j], 0, 0, 0);
        acc[i][j] = __builtin_amdgcn_mfma_f32_16x16x32_f16(ah[i], bl[j], acc[i][j], 0, 0, 0);
        acc[i][j] = __builtin_amdgcn_mfma_f32_16x16x32_f16(al[i], bh[j], acc[i][j], 0, 0, 0);
      }
  }

  #pragma unroll
  for (int j = 0; j < 2; ++j) {
    const int col = bn + wn + j*16 + lr;
    const float bv = bias[col];
    #pragma unroll
    for (int i = 0; i < 2; ++i)
      #pragma unroll
      for (int r4 = 0; r4 < 4; ++r4) {
        const int row = bm + wm + i*16 + lq*4 + r4;
        C[(size_t)row * N + col] = acc[i][j][r4] + bv;
      }
  }
}

// ---------------- GEMM3: out = states @ W_out + b -> fp32 (single f16) ----------------
__global__ __launch_bounds__(256) void gemm3_k(const f16* __restrict__ A,
                                               const f16* __restrict__ Bt,
                                               const float* __restrict__ bias,
                                               float* __restrict__ C) {
  const int K = 256, N = 1024;
  __shared__ f16 sA[4096], sB[4096];

  const int tid = threadIdx.x;
  const int w = tid >> 6, l = tid & 63;
  const int bm = blockIdx.y * 128, bn = blockIdx.x * 128;
  const int wm = (w >> 1) * 64, wn = (w & 1) * 64;
  const int lr = l & 15, lq = l >> 4;

  const f16 *pA[2], *pB[2]; f16 *dA[2], *dB[2];
  #pragma unroll
  for (int p = 0; p < 2; ++p) {
    const int c = p * 256 + tid;
    const int r = c >> 2, k8 = swz(c & 3, r);
    pA[p] = A  + (size_t)(bm + r) * K + k8 * 8;
    pB[p] = Bt + (size_t)(bn + r) * K + k8 * 8;
    dA[p] = sA + (size_t)c * 8;
    dB[p] = sB + (size_t)c * 8;
  }

  int offA[4], offB[4];
  #pragma unroll
  for (int i = 0; i < 4; ++i) {
    const int rowA = wm + i*16 + lr;
    const int rowB = wn + i*16 + lr;
    offA[i] = rowA * 32 + swz(lq, rowA) * 8;
    offB[i] = rowB * 32 + swz(lq, rowB) * 8;
  }

  f32x4 acc[4][4] = {};

  for (int kk = 0; kk < K; kk += 32) {
    __syncthreads();
    glds16(pA[0], dA[0]); glds16(pA[1], dA[1]);
    glds16(pB[0], dB[0]); glds16(pB[1], dB[1]);
    pA[0] += 32; pA[1] += 32; pB[0] += 32; pB[1] += 32;
    asm volatile("s_waitcnt vmcnt(0)" ::: "memory");
    __syncthreads();

    f16x8 af[4], bfr[4];
    #pragma unroll
    for (int i = 0; i < 4; ++i) af[i]  = *(const f16x8*)(sA + offA[i]);
    #pragma unroll
    for (int j = 0; j < 4; ++j) bfr[j] = *(const f16x8*)(sB + offB[j]);
    #pragma unroll
    for (int i = 0; i < 4; ++i)
      #pragma unroll
      for (int j = 0; j < 4; ++j)
        acc[i][j] = __builtin_amdgcn_mfma_f32_16x16x32_f16(af[i], bfr[j], acc[i][j], 0, 0, 0);
  }

  #pragma unroll
  for (int j = 0; j < 4; ++j) {
    const int col = bn + wn + j*16 + lr;
    const float bv = bias[col];
    #pragma unroll
    for (int i = 0; i < 4; ++i)
      #pragma unroll
      for (int r4 = 0; r4 < 4; ++r4) {
        const int row = bm + wm + i*16 + lq*4 + r4;
        C[(size_t)row * N + col] = acc[i][j][r4] + bv;
      }
  }
}

// ---------------- sequential scan: state = silu(state + u_t), fp32 -> f16 states ----------------
// 32 blocks x 64 threads; 3-buffer rotation = loads issued 32 steps ahead.
#define L2E 1.4426950408889634f
__global__ __launch_bounds__(64) void scan_k(const float* __restrict__ upd,
                                             const float* __restrict__ init,
                                             f16* __restrict__ states) {
  const int b = blockIdx.x >> 2, sq = blockIdx.x & 3;
  const int s = sq * 64 + threadIdx.x;
  const float* u = upd + (size_t)b * SEQ * DSZ + s;
  f16* st = states + (size_t)b * SEQ * DSZ + s;
  float state = init[s];

  float r0[16], r1[16], r2[16], ulog[16];
  #pragma unroll
  for (int i = 0; i < 16; ++i) r0[i] = u[(size_t)i * DSZ];
  #pragma unroll
  for (int i = 0; i < 16; ++i) r1[i] = u[(size_t)(16 + i) * DSZ];
  #pragma unroll
  for (int i = 0; i < 16; ++i) ulog[i] = r0[i] * (-L2E);

  for (int t0 = 0; t0 < SEQ; t0 += 16) {
    // loads for t0+32 (two blocks ahead, off the dependency chain)
    if (t0 + 32 < SEQ) {
      #pragma unroll
      for (int i = 0; i < 16; ++i) r2[i] = u[(size_t)(t0 + 32 + i) * DSZ];
    }
    // pure-register dependent chain
    f16 res[16];
    #pragma unroll
    for (int i = 0; i < 16; ++i) {
      const float e = __builtin_amdgcn_exp2f(__builtin_fmaf(state, -L2E, ulog[i]));
      const float x = state + r0[i];
      state = x * __builtin_amdgcn_rcpf(1.0f + e);
      res[i] = (f16)state;
    }
    // stores (off-chain)
    #pragma unroll
    for (int i = 0; i < 16; ++i) st[(size_t)(t0 + i) * DSZ] = res[i];
    // rotate buffers
    #pragma unroll
    for (int i = 0; i < 16; ++i) { r0[i] = r1[i]; ulog[i] = r1[i] * (-L2E); r1[i] = r2[i]; }
  }
}

extern "C" void kernel_launch(void* const* d_in, const int* in_sizes, int n_in,
                              void* d_out, int out_size, void* d_ws, size_t ws_size,
                              hipStream_t stream) {
  const float* x       = (const float*)d_in[0];
  const float* W_in    = (const float*)d_in[1];
  const float* b_in    = (const float*)d_in[2];
  const float* W_state = (const float*)d_in[3];
  const float* b_state = (const float*)d_in[4];
  const float* W_out   = (const float*)d_in[5];
  const float* b_out   = (const float*)d_in[6];
  const float* init_st = (const float*)d_in[7];
  float* out = (float*)d_out;

  char* ws = (char*)d_ws;
  f16*   xh        = (f16*)(ws + 0);             // 32MB [16384][1024]
  f16*   xl        = (f16*)(ws + 33554432);      // 32MB
  f16*   xproj_h   = (f16*)(ws + 67108864);      // 32MB [8192][2048] (per chunk)
  f16*   xproj_l   = (f16*)(ws + 100663296);     // 32MB
  float* upd       = (float*)(ws + 134217728);   // 16MB [16384][256] fp32
  f16*   states    = (f16*)(ws + 150994944);     // 8MB  [16384][256]
  f16*   w_in_h    = (f16*)(ws + 159383552);     // 4MB  [2048][1024]
  f16*   w_in_l    = (f16*)(ws + 163577856);     // 4MB
  f16*   w_state_h = (f16*)(ws + 167772160);     // 1MB  [256][2048]
  f16*   w_state_l = (f16*)(ws + 168820736);     // 1MB
  f16*   w_out_t   = (f16*)(ws + 169869312);     // 0.5MB [1024][256]  (end = 170,393,600 B)

  // 1) pre-split x, transpose+split weights
  split_x_k<<<4096, 256, 0, stream>>>(x, xh, xl, MROWS * DM);
  dim3 tb(32, 8);
  transpose_split_k<<<dim3(DE/32,  DM/32), tb, 0, stream>>>(W_in,    w_in_h,    w_in_l,    DM,  DE);
  transpose_split_k<<<dim3(DSZ/32, DE/32), tb, 0, stream>>>(W_state, w_state_h, w_state_l, DE,  DSZ);
  transpose_cast_f16_k<<<dim3(DM/32, DSZ/32), tb, 0, stream>>>(W_out, w_out_t, DSZ, DM);

  // 2/3) chunked: xproj = silu(x@W_in+b) -> hi/lo f16; upd = xproj@W_state+b -> fp32
  for (int c = 0; c < 2; ++c) {
    const size_t ro = (size_t)c * MCHUNK;
    gemm1_k<<<1024, 512, 0, stream>>>(
        xh + ro * DM, xl + ro * DM, w_in_h, w_in_l, b_in, xproj_h, xproj_l);
    gemm2s_k<<<dim3(DSZ/64, MCHUNK/64), 256, 0, stream>>>(
        xproj_h, xproj_l, w_state_h, w_state_l, b_state, upd + ro * DSZ);
  }

  // 4) sequential scan (fp32), states as f16
  scan_k<<<BATCH*4, 64, 0, stream>>>(upd, init_st, states);

  // 5) out = states @ W_out + b_out -> fp32
  gemm3_k<<<dim3(DM/128, MROWS/128), 256, 0, stream>>>(states, w_out_t, b_out, out);
}